// Round 6
// baseline (186.012 us; speedup 1.0000x reference)
//
#include <hip/hip_runtime.h>
#include <math.h>

// MS-SSIM, 5 levels, fp32, N=32 of 512x512.
// R6: (a) L1-SSIM tiles moved into d1 by inline 2x2 pooling from L0 in
//     registers (breaks pyramid->L1 dependency; kills the ~2048-block serial
//     d2 tail). d2 now only L2-4 (21 x N blocks).
//     (b) unique result slot per tile (plain float2 store) instead of
//     slotted atomics -> no memset node, no contention.
//     (c) pyramid stores only L2/L3/L4 (L1 never materialized).

typedef float v2f __attribute__((ext_vector_type(2)));

#define TILE 32
#define HALO 5
#define SROWS 42   // TILE + 2*HALO
#define SMEM_FLOATS 6728  // hb01 2688f | hb23 2688f | hb4 1344f | red 8f

struct GaussW { float w[11]; };

#define C1_ (0.01f * 0.01f)
#define C2_ (0.03f * 0.03f)

// One 32x32 SSIM tile at level size W. If poolL0, p1/p2 point at the L0
// image (row stride W0 = 2*W) and the level input is pooled on the fly.
__device__ __forceinline__ void ssim_tile(
        const float* __restrict__ p1, const float* __restrict__ p2,
        int W, int W0, bool poolL0,
        int tile_x, int tile_y, const GaussW& gw,
        float2* __restrict__ resslot, float* smem, int tid) {
    v2f* hb01 = (v2f*)smem;                       // [SROWS*TILE]
    v2f* hb23 = (v2f*)(smem + 2 * SROWS * TILE);
    float* hb4 = smem + 4 * SROWS * TILE;
    float* red = smem + 5 * SROWS * TILE;         // [8]

    const bool xfast = (tile_x >= 8) && (tile_x + TILE + 8 <= W);

    // ---- stage A: horizontal blur (packed channels) ----
    for (int it = tid; it < SROWS * 8; it += 256) {
        int r = it >> 3, c4 = it & 7;
        int gy = tile_y + r - HALO;
        int gx0 = tile_x + (c4 << 2) - 8;
        bool rowok = (gy >= 0) && (gy < W);
        float a1[20], a2[20];
#pragma unroll
        for (int i = 0; i < 20; i++) { a1[i] = 0.f; a2[i] = 0.f; }
        if (!poolL0) {
            const float* row1 = p1 + (size_t)gy * W;
            const float* row2 = p2 + (size_t)gy * W;
            if (xfast) {
                if (rowok) {
#pragma unroll
                    for (int q = 0; q < 5; q++) {
                        float4 v1 = *(const float4*)(row1 + gx0 + q * 4);
                        float4 v2v = *(const float4*)(row2 + gx0 + q * 4);
                        a1[q*4+0] = v1.x;  a1[q*4+1] = v1.y;  a1[q*4+2] = v1.z;  a1[q*4+3] = v1.w;
                        a2[q*4+0] = v2v.x; a2[q*4+1] = v2v.y; a2[q*4+2] = v2v.z; a2[q*4+3] = v2v.w;
                    }
                }
            } else {
#pragma unroll
                for (int q = 0; q < 5; q++) {
                    int g = gx0 + q * 4;
                    if (rowok && g >= 0 && g + 4 <= W) {
                        float4 v1 = *(const float4*)(row1 + g);
                        float4 v2v = *(const float4*)(row2 + g);
                        a1[q*4+0] = v1.x;  a1[q*4+1] = v1.y;  a1[q*4+2] = v1.z;  a1[q*4+3] = v1.w;
                        a2[q*4+0] = v2v.x; a2[q*4+1] = v2v.y; a2[q*4+2] = v2v.z; a2[q*4+3] = v2v.w;
                    }
                }
            }
        } else {
            // inline 2x2 pooling from L0 (rows 2gy, 2gy+1; cols 2g..2g+7)
            const float* r10 = p1 + (size_t)(2 * gy) * W0;
            const float* r11 = r10 + W0;
            const float* r20 = p2 + (size_t)(2 * gy) * W0;
            const float* r21 = r20 + W0;
#pragma unroll
            for (int q = 0; q < 5; q++) {
                int g = gx0 + q * 4;
                bool ok = rowok && (xfast || (g >= 0 && g + 4 <= W));
                if (ok) {
                    float4 f0 = *(const float4*)(r10 + 2 * g);
                    float4 f1 = *(const float4*)(r10 + 2 * g + 4);
                    float4 f2 = *(const float4*)(r11 + 2 * g);
                    float4 f3 = *(const float4*)(r11 + 2 * g + 4);
                    a1[q*4+0] = 0.25f * (f0.x + f0.y + f2.x + f2.y);
                    a1[q*4+1] = 0.25f * (f0.z + f0.w + f2.z + f2.w);
                    a1[q*4+2] = 0.25f * (f1.x + f1.y + f3.x + f3.y);
                    a1[q*4+3] = 0.25f * (f1.z + f1.w + f3.z + f3.w);
                    float4 g0 = *(const float4*)(r20 + 2 * g);
                    float4 g1 = *(const float4*)(r20 + 2 * g + 4);
                    float4 g2 = *(const float4*)(r21 + 2 * g);
                    float4 g3 = *(const float4*)(r21 + 2 * g + 4);
                    a2[q*4+0] = 0.25f * (g0.x + g0.y + g2.x + g2.y);
                    a2[q*4+1] = 0.25f * (g0.z + g0.w + g2.z + g2.w);
                    a2[q*4+2] = 0.25f * (g1.x + g1.y + g3.x + g3.y);
                    a2[q*4+3] = 0.25f * (g1.z + g1.w + g3.z + g3.w);
                }
            }
        }
        v2f A[20];
#pragma unroll
        for (int i = 0; i < 20; i++) A[i] = (v2f){a1[i], a2[i]};
        v2f P[14];
        float p12[14];
#pragma unroll
        for (int i = 0; i < 14; i++) {
            v2f u = A[i + 3];
            P[i] = u * u;
            p12[i] = u.x * u.y;
        }
        v2f h01[4] = {(v2f)(0.f), (v2f)(0.f), (v2f)(0.f), (v2f)(0.f)};
        v2f h23[4] = {(v2f)(0.f), (v2f)(0.f), (v2f)(0.f), (v2f)(0.f)};
        float h4[4] = {0.f, 0.f, 0.f, 0.f};
#pragma unroll
        for (int k = 0; k < 11; k++) {
            float wk = gw.w[k];
#pragma unroll
            for (int j = 0; j < 4; j++) {
                h01[j] += wk * A[3 + j + k];
                h23[j] += wk * P[j + k];
                h4[j]  += wk * p12[j + k];
            }
        }
        int ob = r * TILE + (c4 << 2);
#pragma unroll
        for (int j = 0; j < 4; j++) { hb01[ob + j] = h01[j]; hb23[ob + j] = h23[j]; }
        *(float4*)&hb4[ob] = make_float4(h4[0], h4[1], h4[2], h4[3]);
    }
    __syncthreads();

    // ---- stage B: vertical blur (packed) + ssim/mcs ----
    float ssim_v = 0.f, mcs_v = 0.f;
    {
        int tx = tid & 31, y0 = (tid >> 5) * 4;
        v2f m01[4], m23[4];
        float m4[4];
        {
            v2f v[14];
#pragma unroll
            for (int r = 0; r < 14; r++) v[r] = hb01[(y0 + r) * TILE + tx];
#pragma unroll
            for (int j = 0; j < 4; j++) {
                v2f s = (v2f)(0.f);
#pragma unroll
                for (int k = 0; k < 11; k++) s += gw.w[k] * v[j + k];
                m01[j] = s;
            }
        }
        {
            v2f v[14];
#pragma unroll
            for (int r = 0; r < 14; r++) v[r] = hb23[(y0 + r) * TILE + tx];
#pragma unroll
            for (int j = 0; j < 4; j++) {
                v2f s = (v2f)(0.f);
#pragma unroll
                for (int k = 0; k < 11; k++) s += gw.w[k] * v[j + k];
                m23[j] = s;
            }
        }
        {
            float v[14];
#pragma unroll
            for (int r = 0; r < 14; r++) v[r] = hb4[(y0 + r) * TILE + tx];
#pragma unroll
            for (int j = 0; j < 4; j++) {
                float s = 0.f;
#pragma unroll
                for (int k = 0; k < 11; k++) s += gw.w[k] * v[j + k];
                m4[j] = s;
            }
        }
#pragma unroll
        for (int j = 0; j < 4; j++) {
            float mu1 = m01[j].x, mu2 = m01[j].y;
            float mu1sq = mu1 * mu1, mu2sq = mu2 * mu2, mu12 = mu1 * mu2;
            float sg11 = m23[j].x - mu1sq;
            float sg22 = m23[j].y - mu2sq;
            float sg12 = m4[j] - mu12;
            float mcs  = (2.f * sg12 + C2_) / (sg11 + sg22 + C2_);
            float ssim = ((2.f * mu12 + C1_) / (mu1sq + mu2sq + C1_)) * mcs;
            ssim_v += ssim;
            mcs_v  += mcs;
        }
    }

    // ---- block reduction + unique-slot store ----
#pragma unroll
    for (int off = 32; off > 0; off >>= 1) {
        ssim_v += __shfl_down(ssim_v, off);
        mcs_v  += __shfl_down(mcs_v, off);
    }
    int wave = tid >> 6, lane = tid & 63;
    if (lane == 0) { red[wave] = ssim_v; red[4 + wave] = mcs_v; }
    __syncthreads();
    if (tid == 0) {
        float S = red[0] + red[1] + red[2] + red[3];
        float M = red[4] + red[5] + red[6] + red[7];
        *resslot = make_float2(S, M);
    }
}

// pyramid region: 64x64 of L0 -> L1 (LDS only), L2 16x16, L3 8x8, L4 4x4
__device__ __forceinline__ void pyramid_region(
        const float* __restrict__ in1, const float* __restrict__ in2,
        int n, int reg,
        float* __restrict__ l2a, float* __restrict__ l2b,
        float* __restrict__ l3a, float* __restrict__ l3b,
        float* __restrict__ l4a, float* __restrict__ l4b,
        float* smem, int tid) {
    float* b1 = smem;          // 32*32 (L1)
    float* b2 = smem + 1024;
    float* c1 = smem + 2048;   // 16*16 (L2)
    float* c2 = smem + 2304;
    float* d1 = smem + 2560;   // 8*8 (L3)
    float* d2 = smem + 2624;
    const int rx = reg & 7, ry = reg >> 3;
    const float* p1 = in1 + (size_t)n * 512 * 512;
    const float* p2 = in2 + (size_t)n * 512 * 512;

    // L1 (LDS only)
    for (int i = tid; i < 32 * 16; i += 256) {
        int oy = i >> 4, oxp = i & 15;
        int gy = ry * 64 + 2 * oy, gx = rx * 64 + 4 * oxp;
        float4 r10 = *(const float4*)(p1 + (size_t)gy * 512 + gx);
        float4 r11 = *(const float4*)(p1 + (size_t)(gy + 1) * 512 + gx);
        float4 r20 = *(const float4*)(p2 + (size_t)gy * 512 + gx);
        float4 r21 = *(const float4*)(p2 + (size_t)(gy + 1) * 512 + gx);
        *(float2*)&b1[oy * 32 + 2 * oxp] =
            make_float2(0.25f * (r10.x + r10.y + r11.x + r11.y),
                        0.25f * (r10.z + r10.w + r11.z + r11.w));
        *(float2*)&b2[oy * 32 + 2 * oxp] =
            make_float2(0.25f * (r20.x + r20.y + r21.x + r21.y),
                        0.25f * (r20.z + r20.w + r21.z + r21.w));
    }
    __syncthreads();
    // L2 (store)
    if (tid < 16 * 8) {
        int oy = tid >> 3, oxp = tid & 7;
        float4 r10 = *(const float4*)&b1[(2 * oy) * 32 + 4 * oxp];
        float4 r11 = *(const float4*)&b1[(2 * oy + 1) * 32 + 4 * oxp];
        float4 r20 = *(const float4*)&b2[(2 * oy) * 32 + 4 * oxp];
        float4 r21 = *(const float4*)&b2[(2 * oy + 1) * 32 + 4 * oxp];
        float2 o1 = make_float2(0.25f * (r10.x + r10.y + r11.x + r11.y),
                                0.25f * (r10.z + r10.w + r11.z + r11.w));
        float2 o2 = make_float2(0.25f * (r20.x + r20.y + r21.x + r21.y),
                                0.25f * (r20.z + r20.w + r21.z + r21.w));
        *(float2*)&c1[oy * 16 + 2 * oxp] = o1;
        *(float2*)&c2[oy * 16 + 2 * oxp] = o2;
        size_t o = (size_t)n * 128 * 128 + (size_t)(ry * 16 + oy) * 128 + rx * 16 + 2 * oxp;
        *(float2*)&l2a[o] = o1;
        *(float2*)&l2b[o] = o2;
    }
    __syncthreads();
    // L3 (store)
    if (tid < 8 * 4) {
        int oy = tid >> 2, oxp = tid & 3;
        float4 r10 = *(const float4*)&c1[(2 * oy) * 16 + 4 * oxp];
        float4 r11 = *(const float4*)&c1[(2 * oy + 1) * 16 + 4 * oxp];
        float4 r20 = *(const float4*)&c2[(2 * oy) * 16 + 4 * oxp];
        float4 r21 = *(const float4*)&c2[(2 * oy + 1) * 16 + 4 * oxp];
        float2 o1 = make_float2(0.25f * (r10.x + r10.y + r11.x + r11.y),
                                0.25f * (r10.z + r10.w + r11.z + r11.w));
        float2 o2 = make_float2(0.25f * (r20.x + r20.y + r21.x + r21.y),
                                0.25f * (r20.z + r20.w + r21.z + r21.w));
        *(float2*)&d1[oy * 8 + 2 * oxp] = o1;
        *(float2*)&d2[oy * 8 + 2 * oxp] = o2;
        size_t o = (size_t)n * 64 * 64 + (size_t)(ry * 8 + oy) * 64 + rx * 8 + 2 * oxp;
        *(float2*)&l3a[o] = o1;
        *(float2*)&l3b[o] = o2;
    }
    __syncthreads();
    // L4 (store)
    if (tid < 4 * 2) {
        int oy = tid >> 1, oxp = tid & 1;
        float4 r10 = *(const float4*)&d1[(2 * oy) * 8 + 4 * oxp];
        float4 r11 = *(const float4*)&d1[(2 * oy + 1) * 8 + 4 * oxp];
        float4 r20 = *(const float4*)&d2[(2 * oy) * 8 + 4 * oxp];
        float4 r21 = *(const float4*)&d2[(2 * oy + 1) * 8 + 4 * oxp];
        float2 o1 = make_float2(0.25f * (r10.x + r10.y + r11.x + r11.y),
                                0.25f * (r10.z + r10.w + r11.z + r11.w));
        float2 o2 = make_float2(0.25f * (r20.x + r20.y + r21.x + r21.y),
                                0.25f * (r20.z + r20.w + r21.z + r21.w));
        size_t o = (size_t)n * 32 * 32 + (size_t)(ry * 4 + oy) * 32 + rx * 4 + 2 * oxp;
        *(float2*)&l4a[o] = o1;
        *(float2*)&l4b[o] = o2;
    }
}

// D1: t<64 pyramid region; t in [64,320) L0 tile; t in [320,384) L1 tile
// (L1 input pooled inline from L0 -> independent of pyramid blocks).
__global__ __launch_bounds__(256, 4) void d1_kernel(
        const float* __restrict__ i0a, const float* __restrict__ i0b,
        float* __restrict__ l2a, float* __restrict__ l2b,
        float* __restrict__ l3a, float* __restrict__ l3b,
        float* __restrict__ l4a, float* __restrict__ l4b,
        float2* __restrict__ res0, float2* __restrict__ res1, GaussW gw) {
    __shared__ float smem[SMEM_FLOATS];
    const int tid = threadIdx.x;
    const int t = blockIdx.x;
    const int n = blockIdx.y;
    const float* p1 = i0a + (size_t)n * 512 * 512;
    const float* p2 = i0b + (size_t)n * 512 * 512;
    if (t < 64) {
        pyramid_region(i0a, i0b, n, t, l2a, l2b, l3a, l3b, l4a, l4b, smem, tid);
    } else if (t < 320) {
        int idx = t - 64;
        ssim_tile(p1, p2, 512, 512, false, (idx & 15) << 5, (idx >> 4) << 5,
                  gw, &res0[n * 256 + idx], smem, tid);
    } else {
        int idx = t - 320;
        ssim_tile(p1, p2, 256, 512, true, (idx & 7) << 5, (idx >> 3) << 5,
                  gw, &res1[n * 64 + idx], smem, tid);
    }
}

// D2: t<16 L2 tile; t in [16,20) L3; t==20 L4.
__global__ __launch_bounds__(256, 4) void d2_kernel(
        const float* __restrict__ l2a, const float* __restrict__ l2b,
        const float* __restrict__ l3a, const float* __restrict__ l3b,
        const float* __restrict__ l4a, const float* __restrict__ l4b,
        float2* __restrict__ res2, float2* __restrict__ res3,
        float2* __restrict__ res4, GaussW gw) {
    __shared__ float smem[SMEM_FLOATS];
    const int tid = threadIdx.x;
    const int t = blockIdx.x;
    const int n = blockIdx.y;
    const float* b1;
    const float* b2;
    int W, tx, ty;
    float2* slot;
    if (t < 16)      { W = 128; b1 = l2a; b2 = l2b; tx = (t & 3) << 5; ty = (t >> 2) << 5; slot = &res2[n * 16 + t]; }
    else if (t < 20) { int i = t - 16; W = 64; b1 = l3a; b2 = l3b; tx = (i & 1) << 5; ty = (i >> 1) << 5; slot = &res3[n * 4 + i]; }
    else             { W = 32; b1 = l4a; b2 = l4b; tx = 0; ty = 0; slot = &res4[n]; }
    ssim_tile(b1 + (size_t)n * W * W, b2 + (size_t)n * W * W, W, W, false,
              tx, ty, gw, slot, smem, tid);
}

__global__ void finalize_kernel(const float2* __restrict__ res0,
                                const float2* __restrict__ res1,
                                const float2* __restrict__ res2,
                                const float2* __restrict__ res3,
                                const float2* __restrict__ res4,
                                float* __restrict__ out, int N) {
    __shared__ float2 redf[5][4];
    const int tid = threadIdx.x;
    const float2* rr[5] = {res0, res1, res2, res3, res4};
    const int cnts[5] = {N * 256, N * 64, N * 16, N * 4, N};
#pragma unroll
    for (int l = 0; l < 5; l++) {
        float sx = 0.f, sy = 0.f;
        for (int i = tid; i < cnts[l]; i += 256) {
            float2 v = rr[l][i];
            sx += v.x;
            sy += v.y;
        }
#pragma unroll
        for (int off = 32; off > 0; off >>= 1) {
            sx += __shfl_down(sx, off);
            sy += __shfl_down(sy, off);
        }
        if ((tid & 63) == 0) redf[l][tid >> 6] = make_float2(sx, sy);
    }
    __syncthreads();
    if (tid == 0) {
        const float wts[5] = {0.0448f, 0.2856f, 0.3001f, 0.2363f, 0.1333f};
        float r = 1.f;
#pragma unroll
        for (int l = 0; l < 5; l++) {
            float sx = redf[l][0].x + redf[l][1].x + redf[l][2].x + redf[l][3].x;
            float sy = redf[l][0].y + redf[l][1].y + redf[l][2].y + redf[l][3].y;
            int Hl = 512 >> l;
            float cnt = (float)N * (float)Hl * (float)Hl;
            float ssim_m = sx / cnt;
            float mcs_m  = sy / cnt;
            if (l < 4) r *= powf(mcs_m, wts[l]);
            else       r *= powf(ssim_m, wts[4]);
        }
        out[0] = r;
    }
}

extern "C" void kernel_launch(void* const* d_in, const int* in_sizes, int n_in,
                              void* d_out, int out_size, void* d_ws, size_t ws_size,
                              hipStream_t stream) {
    const float* img1 = (const float*)d_in[0];
    const float* img2 = (const float*)d_in[1];
    float* out = (float*)d_out;
    const int HW0 = 512 * 512;
    const int N = in_sizes[0] / HW0;  // 32

    float* base = (float*)d_ws;
    size_t cur = 0;
    float* l2a = base + cur; cur += (size_t)N * 128 * 128;
    float* l2b = base + cur; cur += (size_t)N * 128 * 128;
    float* l3a = base + cur; cur += (size_t)N * 64 * 64;
    float* l3b = base + cur; cur += (size_t)N * 64 * 64;
    float* l4a = base + cur; cur += (size_t)N * 32 * 32;
    float* l4b = base + cur; cur += (size_t)N * 32 * 32;
    float2* res0 = (float2*)(base + cur); cur += (size_t)N * 512;
    float2* res1 = (float2*)(base + cur); cur += (size_t)N * 128;
    float2* res2 = (float2*)(base + cur); cur += (size_t)N * 32;
    float2* res3 = (float2*)(base + cur); cur += (size_t)N * 8;
    float2* res4 = (float2*)(base + cur); cur += (size_t)N * 2;

    GaussW gw;
    {
        double g[11], sum = 0.0;
        for (int i = 0; i < 11; i++) {
            double x = (double)(i - 5);
            g[i] = exp(-(x * x) / (2.0 * 1.5 * 1.5));
            sum += g[i];
        }
        for (int i = 0; i < 11; i++) gw.w[i] = (float)(g[i] / sum);
    }

    d1_kernel<<<dim3(384, N), 256, 0, stream>>>(
        img1, img2, l2a, l2b, l3a, l3b, l4a, l4b, res0, res1, gw);
    d2_kernel<<<dim3(21, N), 256, 0, stream>>>(
        l2a, l2b, l3a, l3b, l4a, l4b, res2, res3, res4, gw);
    finalize_kernel<<<1, 256, 0, stream>>>(res0, res1, res2, res3, res4, out, N);
}